// Round 1
// baseline (10443.679 us; speedup 1.0000x reference)
//
#include <hip/hip_runtime.h>

// Problem constants: B=32, S=1024, I=1024, H=1024, W is (H, I+H) = (1024, 2048)
#define B_ 32
#define S_ 1024
#define H_ 1024
#define NBLK_REC 64

typedef float f32x4 __attribute__((ext_vector_type(4)));
typedef short bf16x8 __attribute__((ext_vector_type(8)));

__device__ __forceinline__ short f2bf(float f) {
  // RNE float -> bf16 bits (inputs finite; NaN path not needed)
  union { float f; unsigned u; } v; v.f = f;
  unsigned r = v.u + 0x7FFFu + ((v.u >> 16) & 1u);
  return (short)(r >> 16);
}

// ============================================================================
// Kernel 1: xz GEMM.  C[m][n] = sum_k x[m][k] * W[n][1024+k] + bias[n]
//   m = b*S+s (row-major match with out[b,s,h]) -> written IN-PLACE into d_out.
//   128x128 tile, BK=32, 4 waves (2x2 of 64x64), mfma_f32_16x16x32_bf16.
//   Reg-staged: load fp32, convert bf16, ds_write_b128. LDS rows padded +8.
// ============================================================================
__global__ __launch_bounds__(256) void xz_gemm(
    const float* __restrict__ X, const float* __restrict__ W,
    const float* __restrict__ bias, float* __restrict__ C) {
  __shared__ short As[128][40];   // pad 40 elems (80B rows) -> bank spread
  __shared__ short Bs[128][40];
  const int tid  = threadIdx.x;
  const int lane = tid & 63, wave = tid >> 6;
  const int m0 = blockIdx.y * 128, n0 = blockIdx.x * 128;
  const int wm = (wave >> 1) * 64, wn = (wave & 1) * 64;
  const int jl = lane & 15, kq = lane >> 4;      // frag row/col + k-quarter
  const int sr = tid >> 2, skg = (tid & 3) * 8;  // staging row / k-group

  f32x4 zero4 = {0.f, 0.f, 0.f, 0.f};
  f32x4 acc[4][4];
  #pragma unroll
  for (int mi = 0; mi < 4; ++mi)
    #pragma unroll
    for (int ni = 0; ni < 4; ++ni) acc[mi][ni] = zero4;

  for (int k0 = 0; k0 < 1024; k0 += 32) {
    #pragma unroll
    for (int rr = 0; rr < 2; ++rr) {
      int row = sr + rr * 64;
      const float* pa = X + (size_t)(m0 + row) * 1024 + k0 + skg;
      f32x4 a0 = *(const f32x4*)pa;
      f32x4 a1 = *(const f32x4*)(pa + 4);
      bf16x8 pk;
      #pragma unroll
      for (int e = 0; e < 4; ++e) { pk[e] = f2bf(a0[e]); pk[e + 4] = f2bf(a1[e]); }
      *(bf16x8*)&As[row][skg] = pk;
      const float* pb = W + (size_t)(n0 + row) * 2048 + 1024 + k0 + skg; // Wx half
      f32x4 b0 = *(const f32x4*)pb;
      f32x4 b1 = *(const f32x4*)(pb + 4);
      bf16x8 qk;
      #pragma unroll
      for (int e = 0; e < 4; ++e) { qk[e] = f2bf(b0[e]); qk[e + 4] = f2bf(b1[e]); }
      *(bf16x8*)&Bs[row][skg] = qk;
    }
    __syncthreads();
    bf16x8 af[4], bf[4];
    // A frag: lane holds A[row=jl][k = kq*8 + e]; B frag: B'[col=jl][k] (B^T input)
    #pragma unroll
    for (int mi = 0; mi < 4; ++mi) af[mi] = *(const bf16x8*)&As[wm + mi * 16 + jl][kq * 8];
    #pragma unroll
    for (int ni = 0; ni < 4; ++ni) bf[ni] = *(const bf16x8*)&Bs[wn + ni * 16 + jl][kq * 8];
    #pragma unroll
    for (int mi = 0; mi < 4; ++mi)
      #pragma unroll
      for (int ni = 0; ni < 4; ++ni)
        acc[mi][ni] = __builtin_amdgcn_mfma_f32_16x16x32_bf16(af[mi], bf[ni], acc[mi][ni], 0, 0, 0);
    __syncthreads();
  }
  // Epilogue: D[row=(lane>>4)*4+r][col=lane&15]  (m89/m91-verified layout)
  #pragma unroll
  for (int ni = 0; ni < 4; ++ni) {
    int col = n0 + wn + ni * 16 + jl;
    float bv = bias[col];
    #pragma unroll
    for (int mi = 0; mi < 4; ++mi) {
      int rbase = m0 + wm + mi * 16 + kq * 4;
      #pragma unroll
      for (int r = 0; r < 4; ++r)
        C[(size_t)(rbase + r) * 1024 + col] = acc[mi][ni][r] + bv;
    }
  }
}

// ============================================================================
// Grid barrier: sense-reversing, device-scope. Conservative: __threadfence()
// (agent acq_rel -> wbl2/inv on gfx950) brackets the arrive/wait so plain
// loads/stores of hbuf are coherent across XCDs.
// ============================================================================
__device__ __forceinline__ void gridbar(unsigned* cnt, unsigned* gen, unsigned nblk) {
  __syncthreads();  // drains each thread's vmem (waitcnt before s_barrier)
  if (threadIdx.x == 0) {
    __threadfence();
    unsigned g = __hip_atomic_load(gen, __ATOMIC_RELAXED, __HIP_MEMORY_SCOPE_AGENT);
    unsigned a = __hip_atomic_fetch_add(cnt, 1u, __ATOMIC_RELAXED, __HIP_MEMORY_SCOPE_AGENT);
    if (a == nblk - 1u) {
      __hip_atomic_store(cnt, 0u, __ATOMIC_RELAXED, __HIP_MEMORY_SCOPE_AGENT);
      __hip_atomic_store(gen, g + 1u, __ATOMIC_RELEASE, __HIP_MEMORY_SCOPE_AGENT);
    } else {
      while (__hip_atomic_load(gen, __ATOMIC_RELAXED, __HIP_MEMORY_SCOPE_AGENT) == g)
        __builtin_amdgcn_s_sleep(2);
    }
    __threadfence();
  }
  __syncthreads();
}

// ============================================================================
// Kernel 2: persistent recurrence. 64 wgs x 512 thr; wg jg owns columns
// [jg*16, jg*16+16) for ALL 32 batches. Wh slice resident in LDS (XOR-swizzled
// bf16). Per step: 8 waves K-split z[32,16] via MFMA, LDS reduce, each thread
// owns one (b,j): gates + c in registers, h -> out (fp32, in-place over xz)
// and ping-pong bf16 hbuf; grid barrier.
// ============================================================================
__global__ __launch_bounds__(512) void lstm_rec(
    const float* __restrict__ W, const float* __restrict__ h0,
    const float* __restrict__ c0, float* __restrict__ out,
    short* __restrict__ hb0, short* __restrict__ hb1,
    unsigned* cnt, unsigned* gen) {
  __shared__ short Whs[16 * 1024];        // 32 KB, swizzled by 16B groups
  __shared__ float zred[8][2][64][4];     // 16 KB: [wave][mtile][lane][reg]
  const int tid  = threadIdx.x;
  const int lane = tid & 63, wave = tid >> 6;
  const int jl = lane & 15, kq = lane >> 4;
  const int jg = blockIdx.x;

  // --- prologue: Wh[jg*16 + j][k], k<1024 -> LDS bf16, group-swizzled
  {
    int j  = tid >> 5;              // 0..15
    int g0 = (tid & 31) * 4;        // group = 8 bf16 (16B)
    const float* wrow = W + (size_t)(jg * 16 + j) * 2048;  // Wh = W[:, :1024]
    #pragma unroll
    for (int g = 0; g < 4; ++g) {
      int grp = g0 + g;
      const float* p = wrow + grp * 8;
      f32x4 a0 = *(const f32x4*)p;
      f32x4 a1 = *(const f32x4*)(p + 4);
      bf16x8 pk;
      #pragma unroll
      for (int e = 0; e < 4; ++e) { pk[e] = f2bf(a0[e]); pk[e + 4] = f2bf(a1[e]); }
      int slot = j * 128 + (grp ^ (j & 7));   // T2-style XOR swizzle (16B units)
      *(bf16x8*)&Whs[slot * 8] = pk;
    }
  }

  // --- owner: every thread owns one (b, j)
  const int b   = tid >> 4;          // 0..31
  const int jj  = tid & 15;
  const int col = jg * 16 + jj;
  float cst  = c0[b * 1024 + col];
  float hcur = h0[b * 1024 + col];
  hb0[b * 1024 + col] = f2bf(hcur);   // 64 wgs jointly init full hbuf0
  gridbar(cnt, gen, NBLK_REC);

  // owner's (row,reg,lane) in the D-fragment of its z element
  const int mtb   = b >> 4;
  const int rowin = b & 15;
  const int lred  = ((rowin >> 2) << 4) | jj;
  const int rred  = rowin & 3;

  for (int t = 0; t < S_; ++t) {
    const short* src = (t & 1) ? hb1 : hb0;
    short*       dst = (t & 1) ? hb0 : hb1;

    // ---- MFMA phase: wave covers K slice [wave*128, +128)
    #pragma unroll
    for (int mt = 0; mt < 2; ++mt) {
      f32x4 pacc = {0.f, 0.f, 0.f, 0.f};
      #pragma unroll
      for (int kk = 0; kk < 4; ++kk) {
        int k = wave * 128 + kk * 32 + kq * 8;
        bf16x8 afrag = *(const bf16x8*)&src[(size_t)(mt * 16 + jl) * 1024 + k];
        int grp = wave * 16 + kk * 4 + kq;
        bf16x8 bfrag = *(const bf16x8*)&Whs[(jl * 128 + (grp ^ (jl & 7))) * 8];
        pacc = __builtin_amdgcn_mfma_f32_16x16x32_bf16(afrag, bfrag, pacc, 0, 0, 0);
      }
      *(f32x4*)&zred[wave][mt][lane][0] = pacc;
    }
    __syncthreads();

    // ---- owner phase: reduce over 8 waves, gates, state update
    float z = 0.f;
    #pragma unroll
    for (int w = 0; w < 8; ++w) z += zred[w][mtb][lred][rred];
    size_t oidx = (size_t)b * (S_ * H_) + (size_t)t * H_ + col;
    z += out[oidx];                                // xz (in-place), read-before-write
    float sg  = 1.f / (1.f + __expf(-z));          // sigmoid(z)
    float e2z = __expf(2.f * z);
    float tz  = 1.f - 2.f / (e2z + 1.f);           // tanh(z)
    cst  = sg * (cst + tz);                        // c = s*(c + tanh z)
    float e2c = __expf(2.f * cst);
    float tc  = 1.f - 2.f / (e2c + 1.f);           // tanh(c)
    hcur = sg * tc;                                // h = s * tanh(c)
    out[oidx] = hcur;
    dst[b * 1024 + col] = f2bf(hcur);
    gridbar(cnt, gen, NBLK_REC);
  }

  // ---- hn, cn
  const size_t OFS = (size_t)B_ * S_ * H_;
  out[OFS + b * 1024 + col] = hcur;
  out[OFS + (size_t)B_ * H_ + b * 1024 + col] = cst;
}

// ============================================================================
extern "C" void kernel_launch(void* const* d_in, const int* in_sizes, int n_in,
                              void* d_out, int out_size, void* d_ws, size_t ws_size,
                              hipStream_t stream) {
  const float* x    = (const float*)d_in[0];   // (B,S,I)
  const float* h0   = (const float*)d_in[1];   // (1,B,H)
  const float* c0   = (const float*)d_in[2];   // (1,B,H)
  const float* W    = (const float*)d_in[3];   // (H, I+H)
  const float* bias = (const float*)d_in[4];   // (H,)
  float* out = (float*)d_out;

  short* hb0 = (short*)d_ws;                   // 32x1024 bf16 ping
  short* hb1 = hb0 + 32 * 1024;                // pong
  unsigned* bar = (unsigned*)((char*)d_ws + 2 * 32 * 1024 * sizeof(short));

  hipMemsetAsync(bar, 0, 2 * sizeof(unsigned), stream);  // cnt, gen
  // xz + bias -> d_out in-place (row m = b*S+s matches out[b,s,:])
  xz_gemm<<<dim3(8, 256), 256, 0, stream>>>(x, W, bias, out);
  // sequential recurrence, persistent grid
  lstm_rec<<<dim3(NBLK_REC), 512, 0, stream>>>(W, h0, c0, out, hb0, hb1, bar, bar + 1);
}

// Round 2
// 5997.666 us; speedup vs baseline: 1.7413x; 1.7413x over previous
//
#include <hip/hip_runtime.h>

// Problem constants: B=32, S=1024, I=1024, H=1024, W is (H, I+H) = (1024, 2048)
#define B_ 32
#define S_ 1024
#define H_ 1024
#define NBLK_REC 64

typedef float f32x4 __attribute__((ext_vector_type(4)));
typedef short bf16x8 __attribute__((ext_vector_type(8)));

__device__ __forceinline__ short f2bf(float f) {
  // RNE float -> bf16 bits (inputs finite)
  union { float f; unsigned u; } v; v.f = f;
  unsigned r = v.u + 0x7FFFu + ((v.u >> 16) & 1u);
  return (short)(r >> 16);
}

// Coherent (L1/L2-bypassing, L3-coherence-point) 16B load. Caller must issue
// s_waitcnt vmcnt(0) + sched_barrier(0) before consuming results (rule 18).
__device__ __forceinline__ f32x4 ldg_coh(const float* p) {
  f32x4 r;
  asm volatile("global_load_dwordx4 %0, %1, off sc0 sc1"
               : "=v"(r) : "v"(p) : "memory");
  return r;
}

// ============================================================================
// Kernel 1: xz GEMM (unchanged from R1, verified).
//   C[m][n] = sum_k x[m][k] * W[n][1024+k] + bias[n], written into d_out.
// ============================================================================
__global__ __launch_bounds__(256) void xz_gemm(
    const float* __restrict__ X, const float* __restrict__ W,
    const float* __restrict__ bias, float* __restrict__ C) {
  __shared__ short As[128][40];
  __shared__ short Bs[128][40];
  const int tid  = threadIdx.x;
  const int lane = tid & 63, wave = tid >> 6;
  const int m0 = blockIdx.y * 128, n0 = blockIdx.x * 128;
  const int wm = (wave >> 1) * 64, wn = (wave & 1) * 64;
  const int jl = lane & 15, kq = lane >> 4;
  const int sr = tid >> 2, skg = (tid & 3) * 8;

  f32x4 zero4 = {0.f, 0.f, 0.f, 0.f};
  f32x4 acc[4][4];
  #pragma unroll
  for (int mi = 0; mi < 4; ++mi)
    #pragma unroll
    for (int ni = 0; ni < 4; ++ni) acc[mi][ni] = zero4;

  for (int k0 = 0; k0 < 1024; k0 += 32) {
    #pragma unroll
    for (int rr = 0; rr < 2; ++rr) {
      int row = sr + rr * 64;
      const float* pa = X + (size_t)(m0 + row) * 1024 + k0 + skg;
      f32x4 a0 = *(const f32x4*)pa;
      f32x4 a1 = *(const f32x4*)(pa + 4);
      bf16x8 pk;
      #pragma unroll
      for (int e = 0; e < 4; ++e) { pk[e] = f2bf(a0[e]); pk[e + 4] = f2bf(a1[e]); }
      *(bf16x8*)&As[row][skg] = pk;
      const float* pb = W + (size_t)(n0 + row) * 2048 + 1024 + k0 + skg;
      f32x4 b0 = *(const f32x4*)pb;
      f32x4 b1 = *(const f32x4*)(pb + 4);
      bf16x8 qk;
      #pragma unroll
      for (int e = 0; e < 4; ++e) { qk[e] = f2bf(b0[e]); qk[e + 4] = f2bf(b1[e]); }
      *(bf16x8*)&Bs[row][skg] = qk;
    }
    __syncthreads();
    bf16x8 af[4], bf[4];
    #pragma unroll
    for (int mi = 0; mi < 4; ++mi) af[mi] = *(const bf16x8*)&As[wm + mi * 16 + jl][kq * 8];
    #pragma unroll
    for (int ni = 0; ni < 4; ++ni) bf[ni] = *(const bf16x8*)&Bs[wn + ni * 16 + jl][kq * 8];
    #pragma unroll
    for (int mi = 0; mi < 4; ++mi)
      #pragma unroll
      for (int ni = 0; ni < 4; ++ni)
        acc[mi][ni] = __builtin_amdgcn_mfma_f32_16x16x32_bf16(af[mi], bf[ni], acc[mi][ni], 0, 0, 0);
    __syncthreads();
  }
  #pragma unroll
  for (int ni = 0; ni < 4; ++ni) {
    int col = n0 + wn + ni * 16 + jl;
    float bv = bias[col];
    #pragma unroll
    for (int mi = 0; mi < 4; ++mi) {
      int rbase = m0 + wm + mi * 16 + kq * 4;
      #pragma unroll
      for (int r = 0; r < 4; ++r)
        C[(size_t)(rbase + r) * 1024 + col] = acc[mi][ni][r] + bv;
    }
  }
}

// ============================================================================
// Kernel 2: barrier-free dataflow recurrence.
//   64 wgs x 512 thr; wg jg owns columns [16jg, 16jg+16) for all 32 batches.
//   h is exchanged THROUGH out[] (fp32): out[b][t][:] is written exactly once
//   (h_{t+1}) and read by consumers at step t+1 — no ping-pong needed.
//   Producer: owners store h via agent-scope atomic f32 (sc0sc1 write-through),
//   __syncthreads() drains vmcnt of every wave, then tid0 bumps flags[jg]
//   (64B-padded). Consumer wave w polls only its 8 K-slice producers, loads h
//   rows via sc0sc1 dwordx4 asm (batched, one vmcnt(0) + sched_barrier(0)),
//   converts to bf16, MFMAs against register-resident Wh fragments.
// ============================================================================
__global__ __launch_bounds__(512) void lstm_rec(
    const float* __restrict__ W, const float* __restrict__ h0,
    const float* __restrict__ c0, float* __restrict__ out,
    unsigned* __restrict__ flags) {
  __shared__ short Whs[16 * 1024];        // 32 KB, XOR-swizzled by 16B groups
  __shared__ float zred[8][2][64][4];     // 16 KB partial-z reduce
  const int tid  = threadIdx.x;
  const int lane = tid & 63, wave = tid >> 6;
  const int jl = lane & 15, kq = lane >> 4;
  const int jg = blockIdx.x;

  // --- prologue: Wh[16jg + j][k] -> LDS bf16, group-swizzled (R1-verified)
  {
    int j  = tid >> 5;
    int g0 = (tid & 31) * 4;
    const float* wrow = W + (size_t)(jg * 16 + j) * 2048;  // Wh = W[:, :1024]
    #pragma unroll
    for (int g = 0; g < 4; ++g) {
      int grp = g0 + g;
      const float* p = wrow + grp * 8;
      f32x4 a0 = *(const f32x4*)p;
      f32x4 a1 = *(const f32x4*)(p + 4);
      bf16x8 pk;
      #pragma unroll
      for (int e = 0; e < 4; ++e) { pk[e] = f2bf(a0[e]); pk[e + 4] = f2bf(a1[e]); }
      int slot = j * 128 + (grp ^ (j & 7));
      *(bf16x8*)&Whs[slot * 8] = pk;
    }
  }
  __syncthreads();

  // --- hoist B-fragments (constant across t): 4 x bf16x8 per wave
  bf16x8 bfr[4];
  #pragma unroll
  for (int kk = 0; kk < 4; ++kk) {
    int grp = wave * 16 + kk * 4 + kq;
    bfr[kk] = *(const bf16x8*)&Whs[(jl * 128 + (grp ^ (jl & 7))) * 8];
  }

  // --- owner: each thread owns one (b, col)
  const int b   = tid >> 4;
  const int jj  = tid & 15;
  const int col = jg * 16 + jj;
  float cst  = c0[b * 1024 + col];
  float hcur = 0.f;
  const int mtb   = b >> 4;
  const int rowin = b & 15;
  const int lred  = ((rowin >> 2) << 4) | jj;
  const int rred  = rowin & 3;

  for (int t = 0; t < S_; ++t) {
    const size_t oidx = (size_t)b * (S_ * H_) + (size_t)t * H_ + col;
    float xz = out[oidx];   // prefetch xz early (stable until our own store)

    // ---- poll: wave w needs producers 8w..8w+7 to have published version t
    if (t && lane < 8) {
      const unsigned* fp = flags + (wave * 8 + lane) * 16;
      while ((int)__hip_atomic_load(fp, __ATOMIC_RELAXED, __HIP_MEMORY_SCOPE_AGENT) < t)
        __builtin_amdgcn_s_sleep(2);
    }

    // ---- batched coherent h loads: A[row=b][k], k in wave's 128-slice
    const float* hbase = t ? (out + (size_t)(t - 1) * H_) : h0;
    const size_t bstr  = t ? (size_t)(S_ * H_) : (size_t)H_;
    f32x4 ua[2][4][2];
    #pragma unroll
    for (int mt = 0; mt < 2; ++mt)
      #pragma unroll
      for (int kk = 0; kk < 4; ++kk) {
        const float* p = hbase + (size_t)(mt * 16 + jl) * bstr
                               + (wave * 128 + kk * 32 + kq * 8);
        ua[mt][kk][0] = ldg_coh(p);
        ua[mt][kk][1] = ldg_coh(p + 4);
      }
    asm volatile("s_waitcnt vmcnt(0)" ::: "memory");
    __builtin_amdgcn_sched_barrier(0);

    // ---- MFMA: convert fp32 h -> bf16 frags, accumulate K-slice partials
    #pragma unroll
    for (int mt = 0; mt < 2; ++mt) {
      f32x4 pacc = {0.f, 0.f, 0.f, 0.f};
      #pragma unroll
      for (int kk = 0; kk < 4; ++kk) {
        bf16x8 af;
        #pragma unroll
        for (int e = 0; e < 4; ++e) {
          af[e]     = f2bf(ua[mt][kk][0][e]);
          af[e + 4] = f2bf(ua[mt][kk][1][e]);
        }
        pacc = __builtin_amdgcn_mfma_f32_16x16x32_bf16(af, bfr[kk], pacc, 0, 0, 0);
      }
      *(f32x4*)&zred[wave][mt][lane][0] = pacc;
    }
    __syncthreads();

    // ---- owner: reduce 8 waves, gates, state update, publish
    float z = xz;
    #pragma unroll
    for (int w = 0; w < 8; ++w) z += zred[w][mtb][lred][rred];
    float sg  = 1.f / (1.f + __expf(-z));          // sigmoid(z)
    float e2z = __expf(2.f * z);
    float tz  = 1.f - 2.f / (e2z + 1.f);           // tanh(z)
    cst  = sg * (cst + tz);                        // c = s*(c + tanh z)
    float e2c = __expf(2.f * cst);
    float tc  = 1.f - 2.f / (e2c + 1.f);           // tanh(c)
    hcur = sg * tc;                                // h = s * tanh(c)
    // write-through to coherence point; doubles as output and h-exchange
    __hip_atomic_store(&out[oidx], hcur, __ATOMIC_RELAXED, __HIP_MEMORY_SCOPE_AGENT);
    __syncthreads();   // drains each wave's vmcnt -> all h stores globally visible
    if (tid == 0)
      __hip_atomic_store(&flags[jg * 16], (unsigned)(t + 1),
                         __ATOMIC_RELAXED, __HIP_MEMORY_SCOPE_AGENT);
    // (zred reuse is safe: next write happens after this barrier)
  }

  // ---- hn, cn
  const size_t OFS = (size_t)B_ * S_ * H_;
  out[OFS + b * 1024 + col] = hcur;
  out[OFS + (size_t)B_ * H_ + b * 1024 + col] = cst;
}

// ============================================================================
extern "C" void kernel_launch(void* const* d_in, const int* in_sizes, int n_in,
                              void* d_out, int out_size, void* d_ws, size_t ws_size,
                              hipStream_t stream) {
  const float* x    = (const float*)d_in[0];   // (B,S,I)
  const float* h0   = (const float*)d_in[1];   // (1,B,H)
  const float* c0   = (const float*)d_in[2];   // (1,B,H)
  const float* W    = (const float*)d_in[3];   // (H, I+H)
  const float* bias = (const float*)d_in[4];   // (H,)
  float* out = (float*)d_out;

  unsigned* flags = (unsigned*)d_ws;           // 64 flags, 64B-padded = 4 KB
  hipMemsetAsync(flags, 0, NBLK_REC * 16 * sizeof(unsigned), stream);

  xz_gemm<<<dim3(8, 256), 256, 0, stream>>>(x, W, bias, out);
  lstm_rec<<<dim3(NBLK_REC), 512, 0, stream>>>(W, h0, c0, out, flags);
}

// Round 3
// 2635.275 us; speedup vs baseline: 3.9630x; 2.2759x over previous
//
#include <hip/hip_runtime.h>

// Problem constants: B=32, S=1024, I=1024, H=1024, W is (H, I+H)
#define B_ 32
#define S_ 1024
#define H_ 1024
#define NWG 64          // 2 batch-groups x 32 col-groups
#define EXN (32 * 1024) // one exchange buffer: 32 x 1024 bf16

typedef float f32x4 __attribute__((ext_vector_type(4)));
typedef short bf16x8 __attribute__((ext_vector_type(8)));
typedef unsigned short u16;

__device__ __forceinline__ short f2bf(float f) {
  union { float f; unsigned u; } v; v.f = f;
  unsigned r = v.u + 0x7FFFu + ((v.u >> 16) & 1u);
  return (short)(r >> 16);
}

// Coherent (L1/L2-bypassing) 16B load of a bf16x8 MFMA fragment.
// Caller must vmcnt(0) + sched_barrier(0) before use (rule 18).
__device__ __forceinline__ bf16x8 ldg_coh_b8(const u16* p) {
  bf16x8 r;
  asm volatile("global_load_dwordx4 %0, %1, off sc0 sc1"
               : "=v"(r) : "v"(p) : "memory");
  return r;
}
__device__ __forceinline__ void stg_coh_u16(u16* p, u16 v) {
  asm volatile("global_store_short %0, %1, off sc0 sc1"
               :: "v"(p), "v"(v) : "memory");
}

// ============================================================================
// Kernel 1: xz GEMM (R1-verified, unchanged).
//   C[m][n] = sum_k x[m][k] * W[n][1024+k] + bias[n] -> d_out in-place.
// ============================================================================
__global__ __launch_bounds__(256) void xz_gemm(
    const float* __restrict__ X, const float* __restrict__ W,
    const float* __restrict__ bias, float* __restrict__ C) {
  __shared__ short As[128][40];
  __shared__ short Bs[128][40];
  const int tid  = threadIdx.x;
  const int lane = tid & 63, wave = tid >> 6;
  const int m0 = blockIdx.y * 128, n0 = blockIdx.x * 128;
  const int wm = (wave >> 1) * 64, wn = (wave & 1) * 64;
  const int jl = lane & 15, kq = lane >> 4;
  const int sr = tid >> 2, skg = (tid & 3) * 8;

  f32x4 zero4 = {0.f, 0.f, 0.f, 0.f};
  f32x4 acc[4][4];
  #pragma unroll
  for (int mi = 0; mi < 4; ++mi)
    #pragma unroll
    for (int ni = 0; ni < 4; ++ni) acc[mi][ni] = zero4;

  for (int k0 = 0; k0 < 1024; k0 += 32) {
    #pragma unroll
    for (int rr = 0; rr < 2; ++rr) {
      int row = sr + rr * 64;
      const float* pa = X + (size_t)(m0 + row) * 1024 + k0 + skg;
      f32x4 a0 = *(const f32x4*)pa;
      f32x4 a1 = *(const f32x4*)(pa + 4);
      bf16x8 pk;
      #pragma unroll
      for (int e = 0; e < 4; ++e) { pk[e] = f2bf(a0[e]); pk[e + 4] = f2bf(a1[e]); }
      *(bf16x8*)&As[row][skg] = pk;
      const float* pb = W + (size_t)(n0 + row) * 2048 + 1024 + k0 + skg;
      f32x4 b0 = *(const f32x4*)pb;
      f32x4 b1 = *(const f32x4*)(pb + 4);
      bf16x8 qk;
      #pragma unroll
      for (int e = 0; e < 4; ++e) { qk[e] = f2bf(b0[e]); qk[e + 4] = f2bf(b1[e]); }
      *(bf16x8*)&Bs[row][skg] = qk;
    }
    __syncthreads();
    bf16x8 af[4], bfv[4];
    #pragma unroll
    for (int mi = 0; mi < 4; ++mi) af[mi] = *(const bf16x8*)&As[wm + mi * 16 + jl][kq * 8];
    #pragma unroll
    for (int ni = 0; ni < 4; ++ni) bfv[ni] = *(const bf16x8*)&Bs[wn + ni * 16 + jl][kq * 8];
    #pragma unroll
    for (int mi = 0; mi < 4; ++mi)
      #pragma unroll
      for (int ni = 0; ni < 4; ++ni)
        acc[mi][ni] = __builtin_amdgcn_mfma_f32_16x16x32_bf16(af[mi], bfv[ni], acc[mi][ni], 0, 0, 0);
    __syncthreads();
  }
  #pragma unroll
  for (int ni = 0; ni < 4; ++ni) {
    int col = n0 + wn + ni * 16 + jl;
    float bv = bias[col];
    #pragma unroll
    for (int mi = 0; mi < 4; ++mi) {
      int rbase = m0 + wm + mi * 16 + kq * 4;
      #pragma unroll
      for (int r = 0; r < 4; ++r)
        C[(size_t)(rbase + r) * 1024 + col] = acc[mi][ni][r] + bv;
    }
  }
}

// ============================================================================
// Kernel 2: dataflow recurrence, bf16 exchange, 2 bg x 32 cg partition.
//   wg (bg,cg) owns z/h for batches [16bg,16bg+16) x cols [32cg,32cg+32).
//   Version v of h lives in exch[v&1] as bf16; flags[wg] = #versions published.
//   Wave w needs k-slice [128w,128w+128) -> polls 4 producers (bg, 4w..4w+3).
//   WAR on the parity buffer is safe: the version-(t+1) store happens after a
//   barrier that transitively confirms all (bg,*) wgs finished step t-1.
// ============================================================================
__global__ __launch_bounds__(512) void lstm_rec(
    const float* __restrict__ W, const float* __restrict__ h0,
    const float* __restrict__ c0, float* __restrict__ out,
    u16* __restrict__ exch, unsigned* __restrict__ flags) {
  __shared__ short Whs[32 * 1024];        // 64 KB bf16, XOR-swizzled 16B groups
  __shared__ float zred[8][2][64][4];     // 16 KB partial-z
  const int tid  = threadIdx.x;
  const int lane = tid & 63, wave = tid >> 6;
  const int jl = lane & 15, kq = lane >> 4;
  const int bg = blockIdx.x >> 5;         // 0..1
  const int cg = blockIdx.x & 31;         // 0..31

  // --- stage Wh[32cg + j][k] (j=0..31) -> LDS bf16, swizzled
  {
    int j  = tid >> 4;                    // 0..31
    int g0 = (tid & 15) * 8;              // 8 groups of 8 floats per thread
    const float* wrow = W + (size_t)(cg * 32 + j) * 2048;   // Wh = W[:, :1024]
    #pragma unroll
    for (int g = 0; g < 8; ++g) {
      int grp = g0 + g;                   // 0..127
      const float* p = wrow + grp * 8;
      f32x4 a0 = *(const f32x4*)p;
      f32x4 a1 = *(const f32x4*)(p + 4);
      bf16x8 pk;
      #pragma unroll
      for (int e = 0; e < 4; ++e) { pk[e] = f2bf(a0[e]); pk[e + 4] = f2bf(a1[e]); }
      *(bf16x8*)&Whs[(j * 128 + (grp ^ (j & 7))) * 8] = pk;
    }
  }

  // --- owner thread: (b', col') ; publish version 0 = bf16(h0)
  const int bp   = tid >> 5;              // 0..15
  const int cp   = tid & 31;              // 0..31
  const int b    = bg * 16 + bp;
  const int col  = cg * 32 + cp;
  float cst  = c0[b * 1024 + col];
  float hcur = 0.f;
  stg_coh_u16(exch + b * 1024 + col, (u16)f2bf(h0[b * 1024 + col]));
  __syncthreads();                        // drains LDS writes + exch stores
  if (tid == 0)
    __hip_atomic_store(&flags[blockIdx.x * 16], 1u,
                       __ATOMIC_RELAXED, __HIP_MEMORY_SCOPE_AGENT);

  // --- hoist B-fragments: [ct][kk], constant across t
  bf16x8 bfr[2][4];
  #pragma unroll
  for (int ct = 0; ct < 2; ++ct)
    #pragma unroll
    for (int kk = 0; kk < 4; ++kk) {
      int j2  = ct * 16 + jl;
      int grp = wave * 16 + kk * 4 + kq;
      bfr[ct][kk] = *(const bf16x8*)&Whs[(j2 * 128 + (grp ^ (j2 & 7))) * 8];
    }

  const int ct_o = cp >> 4;
  const int j16  = cp & 15;
  const int lred = ((bp >> 2) << 4) | j16;
  const int rred = bp & 3;
  const size_t obase = (size_t)b * (S_ * H_) + col;
  const u16* aptr = exch + (size_t)(bg * 16 + jl) * 1024 + wave * 128 + kq * 8;

  for (int t = 0; t < S_; ++t) {
    float xz = out[obase + (size_t)t * H_];   // plain cached load, own elem

    // ---- poll 4 producers of this wave's k-slice for version t
    if (lane < 4) {
      const unsigned* fp = flags + ((bg << 5) | (wave * 4 + lane)) * 16;
      while (__hip_atomic_load(fp, __ATOMIC_RELAXED, __HIP_MEMORY_SCOPE_AGENT)
             < (unsigned)(t + 1))
        __builtin_amdgcn_s_sleep(1);
    }

    // ---- coherent bf16 A-fragment loads (4 x 16B)
    const u16* src = aptr + (t & 1) * EXN;
    bf16x8 afr[4];
    #pragma unroll
    for (int kk = 0; kk < 4; ++kk) afr[kk] = ldg_coh_b8(src + kk * 32);
    asm volatile("s_waitcnt vmcnt(0)" ::: "memory");
    __builtin_amdgcn_sched_barrier(0);

    // ---- MFMA partials into zred
    #pragma unroll
    for (int ct = 0; ct < 2; ++ct) {
      f32x4 pacc = {0.f, 0.f, 0.f, 0.f};
      #pragma unroll
      for (int kk = 0; kk < 4; ++kk)
        pacc = __builtin_amdgcn_mfma_f32_16x16x32_bf16(afr[kk], bfr[ct][kk], pacc, 0, 0, 0);
      *(f32x4*)&zred[wave][ct][lane][0] = pacc;
    }
    __syncthreads();

    // ---- owner: reduce, gates, publish
    float z = xz;
    #pragma unroll
    for (int w = 0; w < 8; ++w) z += zred[w][ct_o][lred][rred];
    float sg  = 1.f / (1.f + __expf(-z));
    float e2z = __expf(2.f * z);
    float tz  = 1.f - 2.f / (e2z + 1.f);
    cst  = sg * (cst + tz);
    float e2c = __expf(2.f * cst);
    float tc  = 1.f - 2.f / (e2c + 1.f);
    hcur = sg * tc;
    stg_coh_u16(exch + ((t + 1) & 1) * EXN + b * 1024 + col, (u16)f2bf(hcur));
    __syncthreads();                      // all exch stores acked (vmcnt drain)
    if (tid == 0)
      __hip_atomic_store(&flags[blockIdx.x * 16], (unsigned)(t + 2),
                         __ATOMIC_RELAXED, __HIP_MEMORY_SCOPE_AGENT);
    out[obase + (size_t)t * H_] = hcur;   // plain store, off the flag path
  }

  // ---- hn, cn
  const size_t OFS = (size_t)B_ * S_ * H_;
  out[OFS + b * 1024 + col] = hcur;
  out[OFS + (size_t)B_ * H_ + b * 1024 + col] = cst;
}

// ============================================================================
extern "C" void kernel_launch(void* const* d_in, const int* in_sizes, int n_in,
                              void* d_out, int out_size, void* d_ws, size_t ws_size,
                              hipStream_t stream) {
  const float* x    = (const float*)d_in[0];
  const float* h0   = (const float*)d_in[1];
  const float* c0   = (const float*)d_in[2];
  const float* W    = (const float*)d_in[3];
  const float* bias = (const float*)d_in[4];
  float* out = (float*)d_out;

  u16* exch = (u16*)d_ws;                               // 2 x 64 KB ping-pong
  unsigned* flags = (unsigned*)((char*)d_ws + 2 * EXN * sizeof(u16));
  hipMemsetAsync(flags, 0, NWG * 16 * sizeof(unsigned), stream);

  xz_gemm<<<dim3(8, 256), 256, 0, stream>>>(x, W, bias, out);
  lstm_rec<<<dim3(NWG), 512, 0, stream>>>(W, h0, c0, out, exch, flags);
}